// Round 19
// baseline (484.525 us; speedup 1.0000x reference)
//
#include <hip/hip_runtime.h>

typedef _Float16 f16;
typedef f16 f16x8 __attribute__((ext_vector_type(8)));
typedef float f32x4 __attribute__((ext_vector_type(4)));

#define EPSBN 1e-3f

enum { EPI_GLU = 2, EPI_OUT = 3 };

// async global->LDS, 16B per lane; lds dest is wave-uniform base (+lane*16 by HW)
__device__ __forceinline__ void stage16(const f16* g, const f16* l) {
    __builtin_amdgcn_global_load_lds(
        (const __attribute__((address_space(1))) unsigned int*)g,
        (__attribute__((address_space(3))) unsigned int*)l,
        16, 0, 0);
}

// Swizzled staging of a [R][32]-f16 K-tile as 16B chunks. LDS slot c holds
// chunk(row=c>>2, kc=(c^(c>>3))&3); chunk(row,kc) sits at slot row*4+(kc^((row>>1)&3)).
__device__ __forceinline__ void stage_swz(const f16* src, int Ksrc, int k0,
                                          const f16* lds, int g, int lane) {
    const int c = g * 64 + lane;
    const int row = c >> 2;
    const int kc = (c ^ (c >> 3)) & 3;
    stage16(src + (size_t)row * Ksrc + k0 + kc * 8, lds + g * 512);
}
// f16 offset of fragment chunk (row, kc=lq); lrh = (lr>>1)&3 (lane-const)
__device__ __forceinline__ int swz_off(int row, int lq, int lrh) {
    return (row * 4 + (lq ^ lrh)) * 8;
}

// ---------------- prep: fold BN into weights, transpose to [N][K] f16, cvt inputs ----------------
__global__ __launch_bounds__(256) void prep_kernel(
    const float* __restrict__ inputs,
    const float* __restrict__ att_w, const float* __restrict__ att_gamma,
    const float* __restrict__ att_beta, const float* __restrict__ att_mean,
    const float* __restrict__ att_var,
    const float* __restrict__ proj_w,
    const float* __restrict__ glu_w, const float* __restrict__ glu_gamma,
    const float* __restrict__ glu_beta, const float* __restrict__ glu_mean,
    const float* __restrict__ glu_var,
    const float* __restrict__ out_w,
    f16* __restrict__ inputs16,
    f16* __restrict__ watt, f16* __restrict__ wproj, f16* __restrict__ wglu,
    f16* __restrict__ wout, float* __restrict__ t_att, float* __restrict__ t_glu)
{
    int tid = blockIdx.x * blockDim.x + threadIdx.x;
    int nth = gridDim.x * blockDim.x;
    for (int i = tid; i < 65536 * 512 / 8; i += nth) {
        float4 u0 = ((const float4*)inputs)[i * 2];
        float4 u1 = ((const float4*)inputs)[i * 2 + 1];
        f16x8 h = {(f16)u0.x, (f16)u0.y, (f16)u0.z, (f16)u0.w,
                   (f16)u1.x, (f16)u1.y, (f16)u1.z, (f16)u1.w};
        ((f16x8*)inputs16)[i] = h;
    }
    for (int i = tid; i < 512 * 512; i += nth) {
        int n = i >> 9, k = i & 511;
        float s = att_gamma[n] * rsqrtf(att_var[n] + EPSBN);
        watt[i] = (f16)(att_w[k * 512 + n] * s);
    }
    for (int i = tid; i < 256 * 512; i += nth) {
        int n = i >> 9, k = i & 511;
        wproj[i] = (f16)(proj_w[k * 256 + n]);
    }
    for (int i = tid; i < 4 * 512 * 256; i += nth) {
        int g = i >> 17, r = i & 131071;
        int n = r >> 8, k = r & 255;
        int c = (n & 1) ? 256 + (n >> 1) : (n >> 1);
        float s = glu_gamma[g * 512 + c] * rsqrtf(glu_var[g * 512 + c] + EPSBN);
        wglu[i] = (f16)(glu_w[g * 131072 + k * 512 + c] * s);
    }
    for (int i = tid; i < 128 * 256; i += nth) {
        int n = i >> 8, k = i & 255;
        wout[i] = (f16)(out_w[k * 128 + n]);
    }
    for (int n = tid; n < 512; n += nth) {
        float s = att_gamma[n] * rsqrtf(att_var[n] + EPSBN);
        t_att[n] = att_beta[n] - att_mean[n] * s;
    }
    for (int i = tid; i < 4 * 512; i += nth) {
        int g = i >> 9, n = i & 511;
        int c = (n & 1) ? 256 + (n >> 1) : (n >> 1);
        float s = glu_gamma[g * 512 + c] * rsqrtf(glu_var[g * 512 + c] + EPSBN);
        t_glu[i] = glu_beta[g * 512 + c] - glu_mean[g * 512 + c] * s;
    }
}

// ---------------- att v6: GEMM + sparsemax + proj, 36.9KB LDS (round-16, measured ~180us) ----------------
__global__ __launch_bounds__(256, 2) void att_sparsemax_kernel(
    const f16* __restrict__ in16, const f16* __restrict__ watt,
    const float* __restrict__ t_att, const float* __restrict__ priors,
    const f16* __restrict__ wproj, const float* __restrict__ proj_b,
    float* __restrict__ maskout, float* __restrict__ npout,
    f16* __restrict__ x0out)
{
    __shared__ f16 S[18432];          // GEMM: A=[0,2048) B=[2048,18432); proj Mld=[0,16896)
    f16* Abuf = S;
    f16* Bbuf = S + 2048;
    const int rBase = blockIdx.x * 64;
    const int tid = threadIdx.x;
    const int lane = tid & 63;
    const int w = tid >> 6;
    const int lr = lane & 15, lq = lane >> 4;
    const int lrh = (lr >> 1) & 3;

    f32x4 acc[32];
#pragma unroll
    for (int n = 0; n < 32; n++) acc[n] = (f32x4){0.f, 0.f, 0.f, 0.f};

    const f16* Asrc = in16 + (size_t)rBase * 512;
#pragma unroll 1
    for (int k = 0; k < 16; k++) {
        __syncthreads();
        stage_swz(Asrc, 512, k * 32, Abuf, w, lane);           // 64x32: 256 chunks
#pragma unroll
        for (int i = 0; i < 8; i++)                             // 512x32: 2048 chunks
            stage_swz(watt, 512, k * 32, Bbuf, w * 8 + i, lane);
        __syncthreads();
        f16x8 af = *(const f16x8*)&Abuf[swz_off(w * 16 + lr, lq, lrh)];
#pragma unroll
        for (int n = 0; n < 32; n++) {
            f16x8 bf = *(const f16x8*)&Bbuf[swz_off(n * 16 + lr, lq, lrh)];
            acc[n] = __builtin_amdgcn_mfma_f32_16x16x32_f16(af, bf, acc[n], 0, 0, 0);
        }
    }

    // z = (acc + t) * priors
#pragma unroll
    for (int n = 0; n < 32; n++) {
        const float t = t_att[n * 16 + lr];
        const size_t pb = (size_t)(rBase + w * 16 + lq * 4) * 512 + n * 16 + lr;
#pragma unroll
        for (int j = 0; j < 4; j++)
            acc[n][j] = (acc[n][j] + t) * priors[pb + (size_t)j * 512];
    }

    // sparsemax (16-lane groups, 4 rows via j)
    float lo[4], hi[4];
#pragma unroll
    for (int j = 0; j < 4; j++) {
        float m = acc[0][j];
#pragma unroll
        for (int n = 1; n < 32; n++) m = fmaxf(m, acc[n][j]);
#pragma unroll
        for (int d = 1; d < 16; d <<= 1) m = fmaxf(m, __shfl_xor(m, d, 64));
        lo[j] = m - 1.f; hi[j] = m;
    }
    for (int it = 0; it < 10; ++it) {
#pragma unroll
        for (int j = 0; j < 4; j++) {
            const float tau = 0.5f * (lo[j] + hi[j]);
            float s = 0.f;
#pragma unroll
            for (int n = 0; n < 32; n++) s += fmaxf(acc[n][j] - tau, 0.f);
#pragma unroll
            for (int d = 1; d < 16; d <<= 1) s += __shfl_xor(s, d, 64);
            if (s >= 1.f) lo[j] = tau; else hi[j] = tau;
        }
    }
    float tau[4];
#pragma unroll
    for (int j = 0; j < 4; j++) {
        float cnt = 0.f, sm = 0.f;
#pragma unroll
        for (int n = 0; n < 32; n++) {
            if (acc[n][j] > lo[j]) { cnt += 1.f; sm += acc[n][j]; }
        }
#pragma unroll
        for (int d = 1; d < 16; d <<= 1) {
            cnt += __shfl_xor(cnt, d, 64);
            sm += __shfl_xor(sm, d, 64);
        }
        tau[j] = (sm - 1.f) / cnt;
    }

    // mask into acc; write mask, np
#pragma unroll
    for (int n = 0; n < 32; n++) {
        const size_t pb = (size_t)(rBase + w * 16 + lq * 4) * 512 + n * 16 + lr;
#pragma unroll
        for (int j = 0; j < 4; j++) {
            const float mk = fmaxf(acc[n][j] - tau[j], 0.f);
            acc[n][j] = mk;
            maskout[pb + (size_t)j * 512] = mk;
            npout[pb + (size_t)j * 512] = priors[pb + (size_t)j * 512] * (1.f - mk);
        }
    }

    // per half: repack mask -> masked (LDS), proj partial-K with direct-L2 B + prefetch
    f16* Mld = S;   // [64][264]
    f32x4 apr[4][4];
#pragma unroll
    for (int m = 0; m < 4; m++)
#pragma unroll
        for (int n = 0; n < 4; n++) apr[m][n] = (f32x4){0.f, 0.f, 0.f, 0.f};
    const f16* Wpb = wproj + (size_t)(w * 64 + lr) * 512 + lq * 8;
#pragma unroll
    for (int h = 0; h < 2; h++) {
        __syncthreads();
#pragma unroll
        for (int i = 0; i < 16; i++) {
            const int n = h * 16 + i;       // static index (rule #20)
            const int colh = i * 16 + lr;
#pragma unroll
            for (int j = 0; j < 4; j++)
                Mld[(w * 16 + lq * 4 + j) * 264 + colh] = (f16)acc[n][j];
        }
        __syncthreads();
#pragma unroll
        for (int i = 0; i < 8; i++) {
            const int c = i * 256 + tid;
            const int row = c >> 5, col8 = (c & 31) * 8;
            f16x8 mv = *(const f16x8*)&Mld[row * 264 + col8];
            f16x8 xv = *(const f16x8*)(in16 + (size_t)(rBase + row) * 512 + h * 256 + col8);
            *(f16x8*)&Mld[row * 264 + col8] = mv * xv;
        }
        __syncthreads();
        f16x8 bcur[4];
#pragma unroll
        for (int n = 0; n < 4; n++)
            bcur[n] = *(const f16x8*)(Wpb + (size_t)(n * 16) * 512 + h * 256);
#pragma unroll
        for (int kk = 0; kk < 8; kk++) {
            f16x8 bnxt[4];
            if (kk + 1 < 8) {
#pragma unroll
                for (int n = 0; n < 4; n++)
                    bnxt[n] = *(const f16x8*)(Wpb + (size_t)(n * 16) * 512 + h * 256 + (kk + 1) * 32);
            }
            f16x8 af[4];
#pragma unroll
            for (int m = 0; m < 4; m++)
                af[m] = *(const f16x8*)&Mld[(m * 16 + lr) * 264 + kk * 32 + lq * 8];
#pragma unroll
            for (int m = 0; m < 4; m++)
#pragma unroll
                for (int n = 0; n < 4; n++)
                    apr[m][n] = __builtin_amdgcn_mfma_f32_16x16x32_f16(af[m], bcur[n], apr[m][n], 0, 0, 0);
            if (kk + 1 < 8) {
#pragma unroll
                for (int n = 0; n < 4; n++) bcur[n] = bnxt[n];
            }
        }
    }
    __syncthreads();
#pragma unroll
    for (int n = 0; n < 4; n++) {
        const int col = w * 64 + n * 16 + lr;
        const float t = proj_b[col];
#pragma unroll
        for (int m = 0; m < 4; m++)
#pragma unroll
            for (int j = 0; j < 4; j++)
                Mld[(m * 16 + lq * 4 + j) * 264 + col] = (f16)(apr[m][n][j] + t);
    }
    __syncthreads();
#pragma unroll
    for (int i = 0; i < 8; i++) {
        const int c = i * 256 + tid;
        const int row = c >> 5, col8 = (c & 31) * 8;
        f16x8 v = *(const f16x8*)&Mld[row * 264 + col8];
        *(f16x8*)(x0out + (size_t)(rBase + row) * 256 + col8) = v;
    }
}

// ---------------- m97-style 128x128 MFMA GEMM (round-3 proven, ~30us/launch) ----------------
template <int K, int NBLK, int EPI>
__global__ __launch_bounds__(256) void gemm_kernel(
    const f16* __restrict__ A, const f16* __restrict__ Bt,
    const float* __restrict__ tb, const f16* __restrict__ xold,
    float* __restrict__ outF, f16* __restrict__ outH)
{
    __shared__ f16 Alds[128 * 32];
    __shared__ f16 Blds[128 * 32];
    int wg = blockIdx.x;
    const int chunk = gridDim.x >> 3;
    wg = (wg & 7) * chunk + (wg >> 3);
    const int rBase = (wg / NBLK) * 128;
    const int cBase = (wg % NBLK) * 128;
    const int tid = threadIdx.x;
    const int lane = tid & 63;
    const int w = tid >> 6;
    const int wr = w & 1, wc = w >> 1;
    const int lr = lane & 15, lq = lane >> 4;

    f32x4 acc[4][4];
#pragma unroll
    for (int m = 0; m < 4; m++)
#pragma unroll
        for (int n = 0; n < 4; n++) acc[m][n] = (f32x4){0.f, 0.f, 0.f, 0.f};

    for (int k0 = 0; k0 < K; k0 += 32) {
        __syncthreads();
#pragma unroll
        for (int i = 0; i < 2; i++) {
            const int c = i * 256 + tid;  // chunk over [128][32]: row=c>>2, kc=c&3
            stage16(A + (size_t)(rBase + (c >> 2)) * K + k0 + (c & 3) * 8,
                    (const f16*)((const char*)Alds + (i * 256 + (w << 6)) * 16));
            stage16(Bt + (size_t)(cBase + (c >> 2)) * K + k0 + (c & 3) * 8,
                    (const f16*)((const char*)Blds + (i * 256 + (w << 6)) * 16));
        }
        __syncthreads();
        f16x8 af[4], bf[4];
#pragma unroll
        for (int m = 0; m < 4; m++)
            af[m] = *(const f16x8*)&Alds[(wr * 64 + m * 16 + lr) * 32 + lq * 8];
#pragma unroll
        for (int n = 0; n < 4; n++)
            bf[n] = *(const f16x8*)&Blds[(wc * 64 + n * 16 + lr) * 32 + lq * 8];
#pragma unroll
        for (int m = 0; m < 4; m++)
#pragma unroll
            for (int n = 0; n < 4; n++)
                acc[m][n] = __builtin_amdgcn_mfma_f32_16x16x32_f16(af[m], bf[n], acc[m][n], 0, 0, 0);
    }

#pragma unroll
    for (int m = 0; m < 4; m++) {
#pragma unroll
        for (int n = 0; n < 4; n++) {
            const int Rb = rBase + wr * 64 + m * 16 + lq * 4;
            const int Cc = cBase + wc * 64 + n * 16 + lr;
#pragma unroll
            for (int j = 0; j < 4; j++) {
                const int R = Rb + j;
                float v = acc[m][n][j] + tb[Cc];
                if constexpr (EPI == EPI_GLU) {
                    float o = __shfl_xor(v, 1, 64);  // val<->gate (interleaved cols)
                    if (!(lane & 1)) {
                        const int xi = Cc >> 1;
                        const size_t id = (size_t)R * 256 + xi;
                        float xn = v * (1.f / (1.f + __expf(-o)));
                        outH[id] = (f16)(xn + (float)xold[id]);
                    }
                } else {  // EPI_OUT
                    outF[(size_t)R * 128 + Cc] = v;
                }
            }
        }
    }
}

extern "C" void kernel_launch(void* const* d_in, const int* in_sizes, int n_in,
                              void* d_out, int out_size, void* d_ws, size_t ws_size,
                              hipStream_t stream)
{
    const float* inputs    = (const float*)d_in[0];
    const float* priors    = (const float*)d_in[1];
    const float* att_w     = (const float*)d_in[2];
    const float* att_gamma = (const float*)d_in[3];
    const float* att_beta  = (const float*)d_in[4];
    const float* att_mean  = (const float*)d_in[5];
    const float* att_var   = (const float*)d_in[6];
    const float* proj_w    = (const float*)d_in[7];
    const float* proj_b    = (const float*)d_in[8];
    const float* glu_w     = (const float*)d_in[9];
    const float* glu_gamma = (const float*)d_in[10];
    const float* glu_beta  = (const float*)d_in[11];
    const float* glu_mean  = (const float*)d_in[12];
    const float* glu_var   = (const float*)d_in[13];
    const float* out_w     = (const float*)d_in[14];
    const float* out_b     = (const float*)d_in[15];

    char* ws = (char*)d_ws;
    f16*   watt     = (f16*)(ws + 0);          // 512*512 f16
    f16*   wproj    = (f16*)(ws + 524288);     // 256*512
    f16*   wglu     = (f16*)(ws + 786432);     // 4*512*256
    f16*   wout     = (f16*)(ws + 1835008);    // 128*256
    float* t_att    = (float*)(ws + 1900544);  // 512
    float* t_glu    = (float*)(ws + 1902592);  // 4*512
    f16*   inputs16 = (f16*)(ws + 2097152);    // 65536*512 f16 (64MB)
    f16*   x0buf    = (f16*)(ws + 69206016);   // 65536*256 f16 (32MB)
    f16*   x1buf    = (f16*)(ws + 102760448);  // 65536*256 f16 (32MB)

    float* outp  = (float*)d_out;
    float* maskp = outp + (size_t)65536 * 128;
    float* npp   = maskp + (size_t)65536 * 512;

    prep_kernel<<<2048, 256, 0, stream>>>(inputs, att_w, att_gamma, att_beta, att_mean,
                                          att_var, proj_w, glu_w, glu_gamma, glu_beta,
                                          glu_mean, glu_var, out_w, inputs16,
                                          watt, wproj, wglu, wout, t_att, t_glu);

    att_sparsemax_kernel<<<1024, 256, 0, stream>>>(
        inputs16, watt, t_att, priors, wproj, proj_b, maskp, npp, x0buf);

    gemm_kernel<256, 4, EPI_GLU><<<2048, 256, 0, stream>>>(
        x0buf, wglu, t_glu, x0buf, nullptr, x1buf);
    gemm_kernel<256, 4, EPI_GLU><<<2048, 256, 0, stream>>>(
        x1buf, wglu + 131072, t_glu + 512, x1buf, nullptr, x0buf);
    gemm_kernel<256, 4, EPI_GLU><<<2048, 256, 0, stream>>>(
        x0buf, wglu + 262144, t_glu + 1024, x0buf, nullptr, x1buf);
    gemm_kernel<256, 4, EPI_GLU><<<2048, 256, 0, stream>>>(
        x1buf, wglu + 393216, t_glu + 1536, x1buf, nullptr, x0buf);

    gemm_kernel<256, 1, EPI_OUT><<<512, 256, 0, stream>>>(
        x0buf, wout, out_b, nullptr, outp, nullptr);
}

// Round 20
// 380.331 us; speedup vs baseline: 1.2740x; 1.2740x over previous
//
#include <hip/hip_runtime.h>

typedef _Float16 f16;
typedef f16 f16x8 __attribute__((ext_vector_type(8)));
typedef float f32x4 __attribute__((ext_vector_type(4)));

#define EPSBN 1e-3f

// counted-vmcnt pipeline primitives (att kernel)
#define VM_WAIT_(N) asm volatile("s_waitcnt vmcnt(" #N ")" ::: "memory")
#define VM_WAIT(N) VM_WAIT_(N)
#define VMLG0() asm volatile("s_waitcnt vmcnt(0) lgkmcnt(0)" ::: "memory")
#define BARRIER() do { __builtin_amdgcn_sched_barrier(0); \
                       __builtin_amdgcn_s_barrier(); \
                       __builtin_amdgcn_sched_barrier(0); } while (0)

// async global->LDS, 16B per lane; lds dest is wave-uniform base (+lane*16 by HW)
__device__ __forceinline__ void stage16(const f16* g, const f16* l) {
    __builtin_amdgcn_global_load_lds(
        (const __attribute__((address_space(1))) unsigned int*)g,
        (__attribute__((address_space(3))) unsigned int*)l,
        16, 0, 0);
}

// Swizzled staging of a [R][32]-f16 K-tile as 16B chunks (att kernel). LDS slot c holds
// chunk(row=c>>2, kc=(c^(c>>3))&3); chunk(row,kc) sits at slot row*4+(kc^((row>>1)&3)).
__device__ __forceinline__ void stage_swz(const f16* src, int Ksrc, int k0,
                                          const f16* lds, int g, int lane) {
    const int c = g * 64 + lane;
    const int row = c >> 2;
    const int kc = (c ^ (c >> 3)) & 3;
    stage16(src + (size_t)row * Ksrc + k0 + kc * 8, lds + g * 512);
}
// f16 offset of fragment chunk (row, kc=lq); lrh = (lr>>1)&3 (lane-const)
__device__ __forceinline__ int swz_off(int row, int lq, int lrh) {
    return (row * 4 + (lq ^ lrh)) * 8;
}

// ---------------- prep: fold BN into weights, transpose to [N][K] f16, cvt inputs ----------------
__global__ __launch_bounds__(256) void prep_kernel(
    const float* __restrict__ inputs,
    const float* __restrict__ att_w, const float* __restrict__ att_gamma,
    const float* __restrict__ att_beta, const float* __restrict__ att_mean,
    const float* __restrict__ att_var,
    const float* __restrict__ proj_w,
    const float* __restrict__ glu_w, const float* __restrict__ glu_gamma,
    const float* __restrict__ glu_beta, const float* __restrict__ glu_mean,
    const float* __restrict__ glu_var,
    const float* __restrict__ out_w,
    f16* __restrict__ inputs16,
    f16* __restrict__ watt, f16* __restrict__ wproj, f16* __restrict__ wglu,
    f16* __restrict__ wout, float* __restrict__ t_att, float* __restrict__ t_glu)
{
    int tid = blockIdx.x * blockDim.x + threadIdx.x;
    int nth = gridDim.x * blockDim.x;
    for (int i = tid; i < 65536 * 512 / 8; i += nth) {
        float4 u0 = ((const float4*)inputs)[i * 2];
        float4 u1 = ((const float4*)inputs)[i * 2 + 1];
        f16x8 h = {(f16)u0.x, (f16)u0.y, (f16)u0.z, (f16)u0.w,
                   (f16)u1.x, (f16)u1.y, (f16)u1.z, (f16)u1.w};
        ((f16x8*)inputs16)[i] = h;
    }
    for (int i = tid; i < 512 * 512; i += nth) {
        int n = i >> 9, k = i & 511;
        float s = att_gamma[n] * rsqrtf(att_var[n] + EPSBN);
        watt[i] = (f16)(att_w[k * 512 + n] * s);
    }
    for (int i = tid; i < 256 * 512; i += nth) {
        int n = i >> 9, k = i & 511;
        wproj[i] = (f16)(proj_w[k * 256 + n]);
    }
    for (int i = tid; i < 4 * 512 * 256; i += nth) {
        int g = i >> 17, r = i & 131071;
        int n = r >> 8, k = r & 255;
        int c = (n & 1) ? 256 + (n >> 1) : (n >> 1);
        float s = glu_gamma[g * 512 + c] * rsqrtf(glu_var[g * 512 + c] + EPSBN);
        wglu[i] = (f16)(glu_w[g * 131072 + k * 512 + c] * s);
    }
    for (int i = tid; i < 128 * 256; i += nth) {
        int n = i >> 8, k = i & 255;
        wout[i] = (f16)(out_w[k * 128 + n]);
    }
    for (int n = tid; n < 512; n += nth) {
        float s = att_gamma[n] * rsqrtf(att_var[n] + EPSBN);
        t_att[n] = att_beta[n] - att_mean[n] * s;
    }
    for (int i = tid; i < 4 * 512; i += nth) {
        int g = i >> 9, n = i & 511;
        int c = (n & 1) ? 256 + (n >> 1) : (n >> 1);
        float s = glu_gamma[g * 512 + c] * rsqrtf(glu_var[g * 512 + c] + EPSBN);
        t_glu[i] = glu_beta[g * 512 + c] - glu_mean[g * 512 + c] * s;
    }
}

// ---------------- att (round-15 best): GEMM dbuf counted-vmcnt + sparsemax + proj ----------------
// 256 threads / 4 waves; block tile 64 rows x 512 cols; nt-stores for mask/np.
__global__ __launch_bounds__(256, 2) void att_sparsemax_kernel(
    const f16* __restrict__ in16, const f16* __restrict__ watt,
    const float* __restrict__ t_att, const float* __restrict__ priors,
    const f16* __restrict__ wproj, const float* __restrict__ proj_b,
    float* __restrict__ maskout, float* __restrict__ npout,
    f16* __restrict__ x0out)
{
    __shared__ f16 Abuf[2 * 2048];
    __shared__ f16 Bbuf[2 * 16384];
    const int rBase = blockIdx.x * 64;
    const int tid = threadIdx.x;
    const int lane = tid & 63;
    const int w = tid >> 6;
    const int lr = lane & 15, lq = lane >> 4;
    const int lrh = (lr >> 1) & 3;

    f32x4 acc[32];
#pragma unroll
    for (int n = 0; n < 32; n++) acc[n] = (f32x4){0.f, 0.f, 0.f, 0.f};

    const f16* Asrc = in16 + (size_t)rBase * 512;
    stage_swz(Asrc, 512, 0, Abuf, w, lane);
#pragma unroll
    for (int i = 0; i < 8; i++)
        stage_swz(watt, 512, 0, Bbuf, w * 8 + i, lane);
    VMLG0();
    BARRIER();
#pragma unroll 1
    for (int k = 0; k < 16; k++) {
        const int cur = k & 1;
        if (k + 1 < 16) {
            stage_swz(Asrc, 512, (k + 1) * 32, Abuf + (cur ^ 1) * 2048, w, lane);
#pragma unroll
            for (int i = 0; i < 8; i++)
                stage_swz(watt, 512, (k + 1) * 32, Bbuf + (cur ^ 1) * 16384, w * 8 + i, lane);
            VM_WAIT(9);
        } else {
            VM_WAIT(0);
        }
        BARRIER();
        f16x8 af = *(const f16x8*)&Abuf[cur * 2048 + swz_off(w * 16 + lr, lq, lrh)];
#pragma unroll
        for (int n = 0; n < 32; n++) {
            f16x8 bf = *(const f16x8*)&Bbuf[cur * 16384 + swz_off(n * 16 + lr, lq, lrh)];
            acc[n] = __builtin_amdgcn_mfma_f32_16x16x32_f16(af, bf, acc[n], 0, 0, 0);
        }
        BARRIER();
    }

    // z = (acc + t) * priors
#pragma unroll
    for (int n = 0; n < 32; n++) {
        const float t = t_att[n * 16 + lr];
        const size_t pb = (size_t)(rBase + w * 16 + lq * 4) * 512 + n * 16 + lr;
#pragma unroll
        for (int j = 0; j < 4; j++)
            acc[n][j] = (acc[n][j] + t) * priors[pb + (size_t)j * 512];
    }

    // sparsemax (16-lane groups, 4 rows via j)
    float lo[4], hi[4];
#pragma unroll
    for (int j = 0; j < 4; j++) {
        float m = acc[0][j];
#pragma unroll
        for (int n = 1; n < 32; n++) m = fmaxf(m, acc[n][j]);
#pragma unroll
        for (int d = 1; d < 16; d <<= 1) m = fmaxf(m, __shfl_xor(m, d, 64));
        lo[j] = m - 1.f; hi[j] = m;
    }
    for (int it = 0; it < 10; ++it) {
#pragma unroll
        for (int j = 0; j < 4; j++) {
            const float tau = 0.5f * (lo[j] + hi[j]);
            float s = 0.f;
#pragma unroll
            for (int n = 0; n < 32; n++) s += fmaxf(acc[n][j] - tau, 0.f);
#pragma unroll
            for (int d = 1; d < 16; d <<= 1) s += __shfl_xor(s, d, 64);
            if (s >= 1.f) lo[j] = tau; else hi[j] = tau;
        }
    }
    float tau[4];
#pragma unroll
    for (int j = 0; j < 4; j++) {
        float cnt = 0.f, sm = 0.f;
#pragma unroll
        for (int n = 0; n < 32; n++) {
            if (acc[n][j] > lo[j]) { cnt += 1.f; sm += acc[n][j]; }
        }
#pragma unroll
        for (int d = 1; d < 16; d <<= 1) {
            cnt += __shfl_xor(cnt, d, 64);
            sm += __shfl_xor(sm, d, 64);
        }
        tau[j] = (sm - 1.f) / cnt;
    }

    // mask into acc; nt-store mask, np (streaming, never re-read -> keep L2 for reused data)
#pragma unroll
    for (int n = 0; n < 32; n++) {
        const size_t pb = (size_t)(rBase + w * 16 + lq * 4) * 512 + n * 16 + lr;
#pragma unroll
        for (int j = 0; j < 4; j++) {
            const float mk = fmaxf(acc[n][j] - tau[j], 0.f);
            acc[n][j] = mk;
            __builtin_nontemporal_store(mk, &maskout[pb + (size_t)j * 512]);
            __builtin_nontemporal_store(priors[pb + (size_t)j * 512] * (1.f - mk),
                                        &npout[pb + (size_t)j * 512]);
        }
    }

    // per half: repack mask -> masked (LDS), proj partial-K GEMM (staged Wst)
    f16* Mld = Bbuf;
    f16* Wst = Bbuf + 16896;
    f32x4 apr[4][4];
#pragma unroll
    for (int m = 0; m < 4; m++)
#pragma unroll
        for (int n = 0; n < 4; n++) apr[m][n] = (f32x4){0.f, 0.f, 0.f, 0.f};
#pragma unroll
    for (int h = 0; h < 2; h++) {
        if (h) __syncthreads();
#pragma unroll
        for (int i = 0; i < 16; i++) {
            const int n = h * 16 + i;       // static index (rule #20)
            const int colh = i * 16 + lr;
#pragma unroll
            for (int j = 0; j < 4; j++)
                Mld[(w * 16 + lq * 4 + j) * 264 + colh] = (f16)acc[n][j];
        }
        __syncthreads();
#pragma unroll
        for (int i = 0; i < 8; i++) {
            const int c = i * 256 + tid;
            const int row = c >> 5, col8 = (c & 31) * 8;
            f16x8 mv = *(const f16x8*)&Mld[row * 264 + col8];
            f16x8 xv = *(const f16x8*)(in16 + (size_t)(rBase + row) * 512 + h * 256 + col8);
            *(f16x8*)&Mld[row * 264 + col8] = mv * xv;
        }
        for (int kk = 0; kk < 8; kk++) {
            __syncthreads();
#pragma unroll
            for (int i = 0; i < 4; i++)
                stage_swz(wproj, 512, h * 256 + kk * 32, Wst, w * 4 + i, lane);
            __syncthreads();
            f16x8 af[4], bf[4];
#pragma unroll
            for (int m = 0; m < 4; m++)
                af[m] = *(const f16x8*)&Mld[(m * 16 + lr) * 264 + kk * 32 + lq * 8];
#pragma unroll
            for (int n = 0; n < 4; n++)
                bf[n] = *(const f16x8*)&Wst[swz_off(w * 64 + n * 16 + lr, lq, lrh)];
#pragma unroll
            for (int m = 0; m < 4; m++)
#pragma unroll
                for (int n = 0; n < 4; n++)
                    apr[m][n] = __builtin_amdgcn_mfma_f32_16x16x32_f16(af[m], bf[n], apr[m][n], 0, 0, 0);
        }
    }
    __syncthreads();
#pragma unroll
    for (int n = 0; n < 4; n++) {
        const int col = w * 64 + n * 16 + lr;
        const float t = proj_b[col];
#pragma unroll
        for (int m = 0; m < 4; m++)
#pragma unroll
            for (int j = 0; j < 4; j++)
                Mld[(m * 16 + lq * 4 + j) * 264 + col] = (f16)(apr[m][n][j] + t);
    }
    __syncthreads();
#pragma unroll
    for (int i = 0; i < 8; i++) {
        const int c = i * 256 + tid;
        const int row = c >> 5, col8 = (c & 31) * 8;
        f16x8 v = *(const f16x8*)&Mld[row * 264 + col8];
        *(f16x8*)(x0out + (size_t)(rBase + row) * 256 + col8) = v;
    }
}

// ---------------- chain v5 (round-15 best) + setprio around MFMA clusters ----------------
// 512 threads / 8 waves; 128 rows/block; X[128][264] only LDS; direct-L2 B + prefetch;
// no barriers inside K-loops -> waves drift -> setprio has role diversity to arbitrate (T5).
__global__ __launch_bounds__(512, 2) void chain_kernel(
    const f16* __restrict__ x0g, const f16* __restrict__ wglu,
    const float* __restrict__ t_glu, const f16* __restrict__ wout,
    const float* __restrict__ out_b, float* __restrict__ outp)
{
    __shared__ f16 X[128 * 264];
    const int rBase = blockIdx.x * 128;
    const int tid = threadIdx.x;
    const int lane = tid & 63;
    const int w = tid >> 6;        // 0..7
    const int lr = lane & 15, lq = lane >> 4;

    // load X tile from x0: [128][256] = 4096 16B-chunks / 512 thr
#pragma unroll
    for (int i = 0; i < 8; i++) {
        const int c = i * 512 + tid;
        const int row = c >> 5, col8 = (c & 31) * 8;
        f16x8 v = *(const f16x8*)(x0g + (size_t)(rBase + row) * 256 + col8);
        *(f16x8*)&X[row * 264 + col8] = v;
    }
    __syncthreads();

    // ---- 4 GLU blocks: C 128x512 (interleaved val/gate), wave cols [w*64,+64), K=256 ----
#pragma unroll 1
    for (int g = 0; g < 4; ++g) {
        f32x4 acc[8][4];
#pragma unroll
        for (int m = 0; m < 8; m++)
#pragma unroll
            for (int n = 0; n < 4; n++) acc[m][n] = (f32x4){0.f, 0.f, 0.f, 0.f};
        const f16* Wb = wglu + (size_t)g * 131072 + (size_t)(w * 64 + lr) * 256 + lq * 8;
        f16x8 bcur[4];
#pragma unroll
        for (int n = 0; n < 4; n++)
            bcur[n] = *(const f16x8*)(Wb + (size_t)(n * 16) * 256);
#pragma unroll
        for (int k = 0; k < 8; k++) {
            f16x8 bnxt[4];
            if (k + 1 < 8) {
#pragma unroll
                for (int n = 0; n < 4; n++)
                    bnxt[n] = *(const f16x8*)(Wb + (size_t)(n * 16) * 256 + (k + 1) * 32);
            }
            f16x8 af[8];
#pragma unroll
            for (int m = 0; m < 8; m++)
                af[m] = *(const f16x8*)&X[(m * 16 + lr) * 264 + k * 32 + lq * 8];
            __builtin_amdgcn_s_setprio(1);
#pragma unroll
            for (int m = 0; m < 8; m++)
#pragma unroll
                for (int n = 0; n < 4; n++)
                    acc[m][n] = __builtin_amdgcn_mfma_f32_16x16x32_f16(af[m], bcur[n], acc[m][n], 0, 0, 0);
            __builtin_amdgcn_s_setprio(0);
            if (k + 1 < 8) {
#pragma unroll
                for (int n = 0; n < 4; n++) bcur[n] = bnxt[n];
            }
        }
        __syncthreads();  // all waves' X reads done before in-place update
#pragma unroll
        for (int n = 0; n < 4; n++) {
            const int col = w * 64 + n * 16 + lr;
            const float t = t_glu[g * 512 + col];
#pragma unroll
            for (int m = 0; m < 8; m++)
#pragma unroll
                for (int j = 0; j < 4; j++) {
                    float v = acc[m][n][j] + t;
                    float o = __shfl_xor(v, 1, 64);  // val<->gate (adjacent interleaved cols)
                    if (!(lane & 1)) {
                        const int xi = col >> 1;     // in [w*32,+32): owned by this thread
                        const int row = m * 16 + lq * 4 + j;
                        float xn = v * (1.f / (1.f + __expf(-o)));
                        X[row * 264 + xi] = (f16)(xn + (float)X[row * 264 + xi]);
                    }
                }
        }
        __syncthreads();  // X updated before next GLU reads
    }

    // ---- out: C 128x128, wave cols [w*16,+16), K=256 ----
    {
        f32x4 acc[8];
#pragma unroll
        for (int m = 0; m < 8; m++) acc[m] = (f32x4){0.f, 0.f, 0.f, 0.f};
        const f16* Wb = wout + (size_t)(w * 16 + lr) * 256 + lq * 8;
        f16x8 bcur = *(const f16x8*)(Wb);
#pragma unroll
        for (int k = 0; k < 8; k++) {
            f16x8 bnxt;
            if (k + 1 < 8) bnxt = *(const f16x8*)(Wb + (k + 1) * 32);
            f16x8 af[8];
#pragma unroll
            for (int m = 0; m < 8; m++)
                af[m] = *(const f16x8*)&X[(m * 16 + lr) * 264 + k * 32 + lq * 8];
            __builtin_amdgcn_s_setprio(1);
#pragma unroll
            for (int m = 0; m < 8; m++)
                acc[m] = __builtin_amdgcn_mfma_f32_16x16x32_f16(af[m], bcur, acc[m], 0, 0, 0);
            __builtin_amdgcn_s_setprio(0);
            if (k + 1 < 8) bcur = bnxt;
        }
        const int col = w * 16 + lr;
        const float t = out_b[col];
#pragma unroll
        for (int m = 0; m < 8; m++)
#pragma unroll
            for (int j = 0; j < 4; j++)
                __builtin_nontemporal_store(acc[m][j] + t,
                    &outp[(size_t)(rBase + m * 16 + lq * 4 + j) * 128 + col]);
    }
}

extern "C" void kernel_launch(void* const* d_in, const int* in_sizes, int n_in,
                              void* d_out, int out_size, void* d_ws, size_t ws_size,
                              hipStream_t stream)
{
    const float* inputs    = (const float*)d_in[0];
    const float* priors    = (const float*)d_in[1];
    const float* att_w     = (const float*)d_in[2];
    const float* att_gamma = (const float*)d_in[3];
    const float* att_beta  = (const float*)d_in[4];
    const float* att_mean  = (const float*)d_in[5];
    const float* att_var   = (const float*)d_in[6];
    const float* proj_w    = (const float*)d_in[7];
    const float* proj_b    = (const float*)d_in[8];
    const float* glu_w     = (const float*)d_in[9];
    const float* glu_gamma = (const float*)d_in[10];
    const float* glu_beta  = (const float*)d_in[11];
    const float* glu_mean  = (const float*)d_in[12];
    const float* glu_var   = (const float*)d_in[13];
    const float* out_w     = (const float*)d_in[14];
    const float* out_b     = (const float*)d_in[15];

    char* ws = (char*)d_ws;
    f16*   watt     = (f16*)(ws + 0);          // 512*512 f16
    f16*   wproj    = (f16*)(ws + 524288);     // 256*512
    f16*   wglu     = (f16*)(ws + 786432);     // 4*512*256
    f16*   wout     = (f16*)(ws + 1835008);    // 128*256
    float* t_att    = (float*)(ws + 1900544);  // 512
    float* t_glu    = (float*)(ws + 1902592);  // 4*512
    f16*   inputs16 = (f16*)(ws + 2097152);    // 65536*512 f16 (64MB)
    f16*   x0buf    = (f16*)(ws + 69206016);   // 65536*256 f16 (32MB)

    float* outp  = (float*)d_out;
    float* maskp = outp + (size_t)65536 * 128;
    float* npp   = maskp + (size_t)65536 * 512;

    prep_kernel<<<2048, 256, 0, stream>>>(inputs, att_w, att_gamma, att_beta, att_mean,
                                          att_var, proj_w, glu_w, glu_gamma, glu_beta,
                                          glu_mean, glu_var, out_w, inputs16,
                                          watt, wproj, wglu, wout, t_att, t_glu);

    att_sparsemax_kernel<<<1024, 256, 0, stream>>>(
        inputs16, watt, t_att, priors, wproj, proj_b, maskp, npp, x0buf);

    chain_kernel<<<512, 512, 0, stream>>>(
        x0buf, wglu, t_glu, wout, out_b, outp);
}